// Round 3
// baseline (284.926 us; speedup 1.0000x reference)
//
#include <hip/hip_runtime.h>
#include <stdint.h>

typedef __attribute__((ext_vector_type(8))) short short8;
typedef __attribute__((ext_vector_type(4))) float float4v;

#define HW   4096
#define CC   256
#define SEQQ 32
#define BSZ  32
#define ROWS 64
#define PSTR 48   // padded row stride (shorts) for ctxT/pL: 96 B, 16B-aligned

// bf16 helpers (round-to-nearest-even)
static __device__ __forceinline__ uint16_t f2bf(float f) {
  union { float f; uint32_t u; } v; v.f = f;
  uint32_t r = v.u + 0x7FFFu + ((v.u >> 16) & 1u);
  return (uint16_t)(r >> 16);
}
static __device__ __forceinline__ float bf2f(uint16_t h) {
  union { uint32_t u; float f; } v; v.u = ((uint32_t)h) << 16;
  return v.f;
}

// ---------------------------------------------------------------------------
// Prep: ctx = context @ W  (fp32 accum), split to bf16 hi/lo, transposed copy,
// plus mask -> additive bias (with storage-format autodetection).
// grid: 257 blocks x 256 threads. Blocks 0..255: 4 rows each of the 1024
// (b,s) rows. Block 256: mask.
// ---------------------------------------------------------------------------
extern "C" __global__ __launch_bounds__(256) void prep_kernel(
    const float* __restrict__ ctx_in,   // [32][32][256]
    const float* __restrict__ Wp,       // [256][256]
    const void*  __restrict__ mask,     // [32][32] unknown storage
    float* __restrict__ bias_ws,        // [32][32] f32
    uint16_t* __restrict__ ctx_hi_ws,   // [32][32][256] bf16
    uint16_t* __restrict__ ctx_lo_ws,   // [32][32][256] bf16
    uint16_t* __restrict__ ctxT_ws)     // [32][256][32] bf16
{
  const int t = threadIdx.x;
  if (blockIdx.x == 256) {
    // --- mask storage detection + bias ---
    __shared__ int byteFlag;
    if (t == 0) byteFlag = 0;
    __syncthreads();
    const uint8_t* mb = (const uint8_t*)mask;
    int nz = 0;
    for (int i = t; i < 1024; i += 256)
      if ((i & 3) == 1 && mb[i] != 0) nz = 1;
    if (nz) atomicOr(&byteFlag, 1);
    __syncthreads();
    const bool byteMode = (byteFlag != 0);
    const uint32_t* mw = (const uint32_t*)mask;
    for (int i = t; i < 1024; i += 256) {
      bool m = byteMode ? (mb[i] != 0) : (mw[i] != 0);
      bias_ws[i] = m ? -1e30f : 0.0f;
    }
    return;
  }

  // --- projection: 4 rows of [1024][256] output ---
  const int r0 = blockIdx.x * 4;
  __shared__ float crow[4][CC];
  #pragma unroll
  for (int j = 0; j < 4; ++j)
    crow[j][t] = ctx_in[(size_t)(r0 + j) * CC + t];
  __syncthreads();

  float acc[4] = {0.f, 0.f, 0.f, 0.f};
  for (int d = 0; d < CC; ++d) {
    float wv = Wp[(size_t)d * CC + t];
    #pragma unroll
    for (int j = 0; j < 4; ++j) acc[j] += crow[j][d] * wv;
  }
  #pragma unroll
  for (int j = 0; j < 4; ++j) {
    int row = r0 + j;              // row = b*32 + s
    int bb = row >> 5, ss = row & 31;
    float v = acc[j];
    uint16_t h = f2bf(v);
    uint16_t lo = f2bf(v - bf2f(h));
    ctx_hi_ws[(size_t)row * CC + t] = h;
    ctx_lo_ws[(size_t)row * CC + t] = lo;
    ctxT_ws[((size_t)bb * CC + t) * SEQQ + ss] = h;
  }
}

// ---------------------------------------------------------------------------
// Main fused kernel: per block = one batch b, 64 consecutive spatial rows.
// 4 waves x 16 rows each. Phase1: S = X*ctx^T via split-bf16 MFMA (3 passes).
// Softmax (mask row = n & 31 !!). Phase2: O = P*ctx via bf16 MFMA.
// ---------------------------------------------------------------------------
extern "C" __global__ __launch_bounds__(256) void attn_main(
    const float* __restrict__ x,        // [32][4096][256]
    const uint8_t* __restrict__ ws,
    float* __restrict__ out0,           // weighted_context [32][4096][256]
    float* __restrict__ out1)           // word_attn        [32][4096][32]
{
  const float*    bias_ws   = (const float*)ws;
  const uint16_t* ctx_hi_ws = (const uint16_t*)(ws + 4096);
  const uint16_t* ctx_lo_ws = ctx_hi_ws + BSZ * SEQQ * CC;
  const uint16_t* ctxT_ws   = ctx_lo_ws + BSZ * SEQQ * CC;

  __shared__ __align__(16) uint16_t ctxHi[SEQQ * 264];  // pad 256->264 (528B rows, 16B-aligned)
  __shared__ __align__(16) uint16_t ctxLo[SEQQ * 264];
  __shared__ __align__(16) uint16_t ctxT[CC * PSTR];    // pad 32->48 (96B rows, 16B-aligned)
  __shared__ __align__(16) float    biasL[BSZ * SEQQ];
  __shared__ __align__(16) uint16_t pL[ROWS * PSTR];    // pad 32->48

  const int tid = threadIdx.x;
  const int b   = blockIdx.y;
  const int n0  = blockIdx.x * ROWS;

  // ---- stage ctx slices + bias into LDS ----
  {
    const uint4* s_hi = (const uint4*)(ctx_hi_ws + (size_t)b * SEQQ * CC);
    const uint4* s_lo = (const uint4*)(ctx_lo_ws + (size_t)b * SEQQ * CC);
    const uint4* s_T  = (const uint4*)(ctxT_ws  + (size_t)b * CC * SEQQ);
    // ctxHi/ctxLo: 32 rows x 256 shorts = 1024 uint4 (32 uint4 per row)
    for (int i = tid; i < 1024; i += 256) {
      int row = i >> 5, col = i & 31;
      *(uint4*)&ctxHi[row * 264 + col * 8] = s_hi[i];
      *(uint4*)&ctxLo[row * 264 + col * 8] = s_lo[i];
    }
    // ctxT: 256 rows x 32 shorts = 1024 uint4 (4 uint4 per row)
    for (int i = tid; i < 1024; i += 256) {
      int c = i >> 2, col = i & 3;
      *(uint4*)&ctxT[c * PSTR + col * 8] = s_T[i];
    }
    ((uint4*)biasL)[tid] = ((const uint4*)bias_ws)[tid];  // 256 uint4 = 4KB
  }
  __syncthreads();

  const int w    = tid >> 6;       // wave id 0..3
  const int lane = tid & 63;
  const int l15  = lane & 15;
  const int quad = lane >> 4;
  const int nbase = n0 + w * 16;

  // ---- phase 1: logits via split-bf16 MFMA ----
  float4v acc0 = {0.f, 0.f, 0.f, 0.f};
  float4v acc1 = {0.f, 0.f, 0.f, 0.f};
  const float* xrow = x + ((size_t)b * HW + nbase + l15) * CC + quad * 8;

  for (int k0 = 0; k0 < 8; ++k0) {
    float4 xa = *(const float4*)(xrow + k0 * 32);
    float4 xb = *(const float4*)(xrow + k0 * 32 + 4);
    float xv[8] = {xa.x, xa.y, xa.z, xa.w, xb.x, xb.y, xb.z, xb.w};
    short8 ah, al;
    #pragma unroll
    for (int j = 0; j < 8; ++j) {
      uint16_t h = f2bf(xv[j]);
      ah[j] = (short)h;
      al[j] = (short)f2bf(xv[j] - bf2f(h));
    }
    const int kb = k0 * 32 + quad * 8;
    short8 bh0 = *(const short8*)&ctxHi[l15 * 264 + kb];
    short8 bl0 = *(const short8*)&ctxLo[l15 * 264 + kb];
    short8 bh1 = *(const short8*)&ctxHi[(16 + l15) * 264 + kb];
    short8 bl1 = *(const short8*)&ctxLo[(16 + l15) * 264 + kb];
    acc0 = __builtin_amdgcn_mfma_f32_16x16x32_bf16(ah, bh0, acc0, 0, 0, 0);
    acc0 = __builtin_amdgcn_mfma_f32_16x16x32_bf16(ah, bl0, acc0, 0, 0, 0);
    acc0 = __builtin_amdgcn_mfma_f32_16x16x32_bf16(al, bh0, acc0, 0, 0, 0);
    acc1 = __builtin_amdgcn_mfma_f32_16x16x32_bf16(ah, bh1, acc1, 0, 0, 0);
    acc1 = __builtin_amdgcn_mfma_f32_16x16x32_bf16(ah, bl1, acc1, 0, 0, 0);
    acc1 = __builtin_amdgcn_mfma_f32_16x16x32_bf16(al, bh1, acc1, 0, 0, 0);
  }

  // ---- softmax over 32 logits per row (row m = quad*4+r, col s = l15/+16) ----
  #pragma unroll
  for (int r = 0; r < 4; ++r) {
    const int n  = nbase + quad * 4 + r;
    const int br = n & 31;                     // mask-tile quirk: row = n % 32
    float v0 = acc0[r] + biasL[br * 32 + l15];
    float v1 = acc1[r] + biasL[br * 32 + 16 + l15];
    float mx = fmaxf(v0, v1);
    #pragma unroll
    for (int off = 1; off < 16; off <<= 1)
      mx = fmaxf(mx, __shfl_xor(mx, off, 64));
    float e0 = __expf(v0 - mx);
    float e1 = __expf(v1 - mx);
    float sm = e0 + e1;
    #pragma unroll
    for (int off = 1; off < 16; off <<= 1)
      sm += __shfl_xor(sm, off, 64);
    float inv = 1.0f / sm;
    float p0 = e0 * inv, p1 = e1 * inv;
    size_t o1 = ((size_t)b * HW + n) * SEQQ;
    out1[o1 + l15]      = p0;
    out1[o1 + 16 + l15] = p1;
    pL[(w * 16 + quad * 4 + r) * PSTR + l15]      = f2bf(p0);
    pL[(w * 16 + quad * 4 + r) * PSTR + 16 + l15] = f2bf(p1);
  }
  __syncthreads();   // make pL writes visible before fragment reads

  // ---- phase 2: O = P * ctx  (K=32 in one MFMA per 16x16 tile) ----
  short8 pa = *(const short8*)&pL[(w * 16 + l15) * PSTR + quad * 8];
  #pragma unroll
  for (int ct = 0; ct < 16; ++ct) {
    short8 bfr = *(const short8*)&ctxT[(ct * 16 + l15) * PSTR + quad * 8];
    float4v z = {0.f, 0.f, 0.f, 0.f};
    float4v d = __builtin_amdgcn_mfma_f32_16x16x32_bf16(pa, bfr, z, 0, 0, 0);
    #pragma unroll
    for (int r = 0; r < 4; ++r) {
      size_t o0 = ((size_t)b * HW + nbase + quad * 4 + r) * CC + ct * 16 + l15;
      out0[o0] = d[r];
    }
  }
}

// ---------------------------------------------------------------------------
extern "C" void kernel_launch(void* const* d_in, const int* in_sizes, int n_in,
                              void* d_out, int out_size, void* d_ws, size_t ws_size,
                              hipStream_t stream) {
  const float* x      = (const float*)d_in[0];
  // d_in[1] = sentence (unused by reference call())
  const float* ctx_in = (const float*)d_in[2];
  const void*  mask   = d_in[3];
  const float* Wp     = (const float*)d_in[4];

  float* out0 = (float*)d_out;                       // [32][4096][256]
  float* out1 = out0 + (size_t)BSZ * HW * CC;        // [32][4096][32]

  uint8_t*  ws        = (uint8_t*)d_ws;
  float*    bias_ws   = (float*)ws;                            // 4 KB
  uint16_t* ctx_hi_ws = (uint16_t*)(ws + 4096);                // 512 KB
  uint16_t* ctx_lo_ws = ctx_hi_ws + BSZ * SEQQ * CC;           // 512 KB
  uint16_t* ctxT_ws   = ctx_lo_ws + BSZ * SEQQ * CC;           // 512 KB

  prep_kernel<<<257, 256, 0, stream>>>(ctx_in, Wp, mask, bias_ws,
                                       ctx_hi_ws, ctx_lo_ws, ctxT_ws);
  attn_main<<<dim3(HW / ROWS, BSZ), 256, 0, stream>>>(x, ws, out0, out1);
}